// Round 8
// baseline (1917.115 us; speedup 1.0000x reference)
//
#include <hip/hip_runtime.h>

// RoIAlign matching jax.image.scale_and_translate(method="linear", antialias=True)
// feature_map: [512][512][64] f32, boxes: [512][4] f32 (cx,cy,w,h), out: [512][32][32][64] f32
// Wave-private separable resize, depth-2 pipelined: 3 LDS row-buffers, stage row
// r+2 while computing row r, counted s_waitcnt vmcnt(NGL) via template dispatch.

#define H_IN 512
#define W_IN 512
#define CH   64
#define NB   512
#define OW   32
#define WG   40      // padded weight stride in GLOBAL wTab (zeros at [cnt,40))
#define WYS  33      // y-weight stride in LDS
#define TAPS_MAX 33
#define COLS_B 152   // buffer cols: cux <= 146, overread <= cux+6 (pads zeroed)
#define COLS_CL 146

// ---------------------------------------------------------------------------
// Kernel 1: per (box, dim, o) tap table. Same math as R1-R7 (verified), but
// weights written at stride WG=40 with exact zeros at [cnt, 40) so the main
// kernel can hold them in registers and run fixed 5-chunk FMA loops.
// ---------------------------------------------------------------------------
__global__ __launch_bounds__(256) void roi_weights(const float* __restrict__ boxes,
                                                   float* __restrict__ wTab,
                                                   int* __restrict__ meta) {
    int tid = blockIdx.x * blockDim.x + threadIdx.x;
    if (tid >= NB * 2 * 32) return;
    int o   = tid & 31;
    int dim = (tid >> 5) & 1;   // 0 = y, 1 = x
    int b   = tid >> 6;

    float cx = boxes[b * 4 + 0];
    float cy = boxes[b * 4 + 1];
    float bw = boxes[b * 4 + 2];
    float bh = boxes[b * 4 + 3];
    float cc = dim ? cx : cy;
    float sz = dim ? bw : bh;
    float lo = cc - sz * 0.5f;        // x0/y0 use PRE-clamp size (matches ref)
    sz = fmaxf(sz, 1e-6f);

    float scale = (float)OW / (sz * (float)W_IN);
    float inv   = 1.0f / scale;
    float trans = (-lo * (float)OW) / sz;
    float s     = ((float)o + 0.5f) * inv - trans * inv - 0.5f;
    float ks    = fmaxf(inv, 1.0f);

    int i_lo = max((int)ceilf(s - ks), 0);
    int i_hi = min((int)floorf(s + ks), W_IN - 1);
    int cnt  = i_hi - i_lo + 1;
    if (cnt < 0) cnt = 0;
    if (cnt > TAPS_MAX) cnt = TAPS_MAX;

    float sum = 0.0f;
    for (int k = 0; k < cnt; ++k) {
        float x = fabsf(s - (float)(i_lo + k)) / ks;
        sum += fmaxf(0.0f, 1.0f - x);
    }
    bool ok = (sum > 1.1920929e-4f) && (s >= -0.5f) && (s <= (float)W_IN - 0.5f);

    float* wout = wTab + ((size_t)(dim * NB + b) * 32 + o) * WG;
    for (int k = 0; k < WG; ++k) {
        float w = 0.0f;
        if (ok && k < cnt) {
            float x = fabsf(s - (float)(i_lo + k)) / ks;
            w = fmaxf(0.0f, 1.0f - x) / sum;
        }
        wout[k] = w;
    }
    int* m = meta + ((size_t)(dim * NB + b) * 32 + o) * 2;
    m[0] = i_lo;
    m[1] = ok ? cnt : 0;
}

// direct global->LDS, 16B per lane; LDS dest = wave-uniform base + laneid*16
__device__ __forceinline__ void gload16(const float* src, float* ldsDst) {
    __builtin_amdgcn_global_load_lds((const __attribute__((address_space(1))) void*)src,
                                     (__attribute__((address_space(3))) void*)ldsDst, 16, 0, 0);
}

template<int N> __device__ __forceinline__ void wait_vm() {
    if constexpr (N == 0)  asm volatile("s_waitcnt vmcnt(0)"  ::: "memory");
    if constexpr (N == 1)  asm volatile("s_waitcnt vmcnt(1)"  ::: "memory");
    if constexpr (N == 2)  asm volatile("s_waitcnt vmcnt(2)"  ::: "memory");
    if constexpr (N == 3)  asm volatile("s_waitcnt vmcnt(3)"  ::: "memory");
    if constexpr (N == 4)  asm volatile("s_waitcnt vmcnt(4)"  ::: "memory");
    if constexpr (N == 5)  asm volatile("s_waitcnt vmcnt(5)"  ::: "memory");
    if constexpr (N == 6)  asm volatile("s_waitcnt vmcnt(6)"  ::: "memory");
    if constexpr (N == 7)  asm volatile("s_waitcnt vmcnt(7)"  ::: "memory");
    if constexpr (N == 8)  asm volatile("s_waitcnt vmcnt(8)"  ::: "memory");
    if constexpr (N == 9)  asm volatile("s_waitcnt vmcnt(9)"  ::: "memory");
    if constexpr (N == 10) asm volatile("s_waitcnt vmcnt(10)" ::: "memory");
}

// issue exactly NGL global_load_lds for one row (some lanes exec-masked)
template<int NGL>
__device__ __forceinline__ void stage_row(const float* rowSrc, float* dst,
                                          int laneCol, int cux) {
    #pragma unroll
    for (int b = 0; b < NGL; ++b) {
        if (b * 16 + laneCol < cux)          // b*16 < cux always -> instr issues
            gload16(rowSrc + b * 16 * CH, dst + b * 256);
    }
}

template<int N> struct IC { static constexpr int value = N; };

// ---------------------------------------------------------------------------
// Kernel 2: 1 wave per block; wave = 8 ox x 16 ch x 16 oy.
// bid: box = ((bid>>8)<<3)|(bid&7) -> a box's 32 sub-blocks on one XCD.
// 3 row-buffers: at row r, wait vmcnt(NGL) (row r staged, r+1 may fly),
// issue stage of r+2, compute r. x-weights live in 40 VGPRs (not LDS).
// ---------------------------------------------------------------------------
__global__ __launch_bounds__(64, 2) void roi_pipe(const float* __restrict__ fm,
                                                  const float* __restrict__ wTab,
                                                  const int* __restrict__ meta,
                                                  float* __restrict__ out) {
    __shared__ float sBuf[3][COLS_B * 16];   // 29184 B, [col][16ch] linear per buf
    __shared__ float sWy[16 * WYS];          // 2112 B
    __shared__ int   sMx[16];                // (ix0, cntx) per local ox
    __shared__ int   sMyLC[16];              // i_lo | cnt<<16 per oy
    __shared__ int   sU[4];                  // u0, cu, xu0, cux

    int bid = blockIdx.x;
    int box = ((bid >> 8) << 3) | (bid & 7);
    int sub = (bid >> 3) & 31;
    int ox0 = (sub & 3) * 8;
    int ch0 = ((sub >> 2) & 3) * 16;
    int oy0 = (sub >> 4) * 16;
    int t   = threadIdx.x;

    const float* wysrc = wTab + ((size_t)box * 32 + oy0) * WG;
    for (int i = t; i < 16 * WYS; i += 64) {
        int o = i / WYS, k = i - o * WYS;
        sWy[i] = wysrc[o * WG + k];
    }
    if (t < 16) sMx[t] = meta[((size_t)(NB + box) * 32 + ox0) * 2 + t];
    if (t >= 16 && t < 32) {
        int k  = t - 16;
        int lo = meta[((size_t)box * 32 + oy0 + k) * 2];
        int cn = meta[((size_t)box * 32 + oy0 + k) * 2 + 1];
        sMyLC[k] = (lo & 0xffff) | (cn << 16);
    }
    __syncthreads();
    if (t == 0) {
        int lo = 0x7fffffff, hi = -1;
        for (int k = 0; k < 16; ++k) {
            int lc = sMyLC[k], c = lc >> 16;
            if (c > 0) { int l = lc & 0xffff; lo = min(lo, l); hi = max(hi, l + c); }
        }
        sU[0] = (hi > lo) ? lo : 0;
        sU[1] = (hi > lo) ? (hi - lo) : 0;
        int xlo = 0x7fffffff, xhi = -1;
        for (int k = 0; k < 8; ++k) {
            int c = sMx[2 * k + 1];
            if (c > 0) { int l = sMx[2 * k]; xlo = min(xlo, l); xhi = max(xhi, l + c); }
        }
        sU[2] = (xhi > xlo) ? xlo : 0;
        int cux = (xhi > xlo) ? (xhi - xlo) : 0;
        sU[3] = (cux > COLS_CL) ? COLS_CL : cux;
    }
    __syncthreads();
    int u0 = sU[0], cu = sU[1], xu0 = sU[2], cux = sU[3];

    int ox = t >> 3, cp = t & 7;
    int ix0rel = max(sMx[2 * ox] - xu0, 0);
    int cntx   = sMx[2 * ox + 1];
    int nch    = (cntx + 7) >> 3;            // 0..5

    // x-weights -> 40 VGPRs (global table zero-padded to WG=40)
    const float* wxg = wTab + ((size_t)(NB + box) * 32 + ox0 + ox) * WG;
    float4 wr[10];
    #pragma unroll
    for (int c = 0; c < 5; ++c) {
        wr[2 * c]     = *(const float4*)(wxg + c * 8);
        wr[2 * c + 1] = *(const float4*)(wxg + c * 8 + 4);
    }

    int myLC[16];
    #pragma unroll
    for (int k = 0; k < 16; ++k) myLC[k] = sMyLC[k];

    float accA[16], accB[16];
    #pragma unroll
    for (int k = 0; k < 16; ++k) { accA[k] = 0.f; accB[k] = 0.f; }

    // zero pad cols [cux, cux+8) of all 3 buffers (chunk overread -> exact +0)
    for (int i = t; i < 3 * 8 * 16; i += 64) {
        int b = i >> 7, rem = i & 127;
        int cc = cux + (rem >> 4);
        if (cc < COLS_B) sBuf[b][cc * 16 + (rem & 15)] = 0.0f;
    }

    int laneCol = t >> 2;                    // 16 cols x 16ch per gload16 batch
    const float* laneSrc = fm + (size_t)(xu0 + laneCol) * CH + ch0 + (t & 3) * 4;
    __syncthreads();                         // pads + tables settled

    int ngl = (cux + 15) >> 4;               // wave-uniform, 0..10
    if (cu > 0 && ngl > 0) {
        auto run = [&](auto nglc) {
            constexpr int NGL = decltype(nglc)::value;
            stage_row<NGL>(laneSrc + (size_t)u0 * (W_IN * CH), sBuf[0], laneCol, cux);
            if (cu > 1)
                stage_row<NGL>(laneSrc + (size_t)(u0 + 1) * (W_IN * CH), sBuf[1], laneCol, cux);
            float* bA = sBuf[0];
            float* bB = sBuf[1];
            float* bC = sBuf[2];
            for (int r = 0; r < cu; ++r) {
                wait_vm<NGL>();              // row r staged; r+1 may remain in flight
                if (r + 2 < cu)
                    stage_row<NGL>(laneSrc + (size_t)(u0 + r + 2) * (W_IN * CH), bC, laneCol, cux);
                __builtin_amdgcn_sched_barrier(0);   // keep stage issue before compute

                const float* bp = bA + ix0rel * 16 + cp * 2;
                float xa = 0.f, xb = 0.f;
                #pragma unroll
                for (int c = 0; c < 5; ++c) {
                    if (c < nch) {
                        float2 v[8];
                        #pragma unroll
                        for (int k = 0; k < 8; ++k) v[k] = *(const float2*)(bp + (c * 8 + k) * 16);
                        float4 w0 = wr[2 * c], w1 = wr[2 * c + 1];
                        xa = fmaf(w0.x, v[0].x, xa); xb = fmaf(w0.x, v[0].y, xb);
                        xa = fmaf(w0.y, v[1].x, xa); xb = fmaf(w0.y, v[1].y, xb);
                        xa = fmaf(w0.z, v[2].x, xa); xb = fmaf(w0.z, v[2].y, xb);
                        xa = fmaf(w0.w, v[3].x, xa); xb = fmaf(w0.w, v[3].y, xb);
                        xa = fmaf(w1.x, v[4].x, xa); xb = fmaf(w1.x, v[4].y, xb);
                        xa = fmaf(w1.y, v[5].x, xa); xb = fmaf(w1.y, v[5].y, xb);
                        xa = fmaf(w1.z, v[6].x, xa); xb = fmaf(w1.z, v[6].y, xb);
                        xa = fmaf(w1.w, v[7].x, xa); xb = fmaf(w1.w, v[7].y, xb);
                    }
                }

                int iy = u0 + r;
                #pragma unroll
                for (int oy = 0; oy < 16; ++oy) {
                    int lc = myLC[oy];
                    int rr = iy - (lc & 0xffff);
                    if ((unsigned)rr < (unsigned)(lc >> 16)) {
                        float w = sWy[oy * WYS + rr];
                        accA[oy] = fmaf(w, xa, accA[oy]);
                        accB[oy] = fmaf(w, xb, accB[oy]);
                    }
                }

                float* tmp = bA; bA = bB; bB = bC; bC = tmp;
            }
        };
        switch (ngl) {
            case 1:  run(IC<1>{});  break;
            case 2:  run(IC<2>{});  break;
            case 3:  run(IC<3>{});  break;
            case 4:  run(IC<4>{});  break;
            case 5:  run(IC<5>{});  break;
            case 6:  run(IC<6>{});  break;
            case 7:  run(IC<7>{});  break;
            case 8:  run(IC<8>{});  break;
            case 9:  run(IC<9>{});  break;
            default: run(IC<10>{}); break;
        }
    }

    #pragma unroll
    for (int oy = 0; oy < 16; ++oy) {
        float* op = out + (((size_t)box * 32 + oy0 + oy) * 32 + ox0 + ox) * CH + ch0 + cp * 2;
        *(float2*)op = make_float2(accA[oy], accB[oy]);
    }
}

extern "C" void kernel_launch(void* const* d_in, const int* in_sizes, int n_in,
                              void* d_out, int out_size, void* d_ws, size_t ws_size,
                              hipStream_t stream) {
    const float* fm    = (const float*)d_in[0];
    const float* boxes = (const float*)d_in[1];
    // d_in[2] = output_width (==32), hardcoded.

    float* wTab = (float*)d_ws;                                    // 2*512*32*40 f32 = 5.24 MB
    int*   meta = (int*)((char*)d_ws + (size_t)2 * NB * 32 * WG * sizeof(float)); // 512 KB

    roi_weights<<<(NB * 2 * 32 + 255) / 256, 256, 0, stream>>>(boxes, wTab, meta);
    roi_pipe<<<NB * 32, 64, 0, stream>>>(fm, wTab, meta, (float*)d_out);
}